// Round 5
// baseline (9805.469 us; speedup 1.0000x reference)
//
#include <hip/hip_runtime.h>
#include <hip/hip_cooperative_groups.h>
#include <stdint.h>

namespace cg = cooperative_groups;

#define HH 128
#define WW 128
#define CHN 16
#define NPIX (HH*WW)          // 16384 per batch
#define PLANE (CHN*NPIX)      // 262144 per batch
#define STEPS 64
#define TW 8
#define TH 8

__host__ __device__ __forceinline__ uint32_t rotl32_(uint32_t x, int d) {
  return (x << d) | (x >> (32 - d));
}

__host__ __device__ __forceinline__ void tf2x32(uint32_t k0, uint32_t k1,
                                                uint32_t x0, uint32_t x1,
                                                uint32_t* o0, uint32_t* o1) {
  uint32_t ks0 = k0, ks1 = k1, ks2 = k0 ^ k1 ^ 0x1BD11BDAu;
  x0 += ks0; x1 += ks1;
  x0 += x1; x1 = rotl32_(x1, 13); x1 ^= x0;
  x0 += x1; x1 = rotl32_(x1, 15); x1 ^= x0;
  x0 += x1; x1 = rotl32_(x1, 26); x1 ^= x0;
  x0 += x1; x1 = rotl32_(x1, 6);  x1 ^= x0;
  x0 += ks1; x1 += ks2 + 1u;
  x0 += x1; x1 = rotl32_(x1, 17); x1 ^= x0;
  x0 += x1; x1 = rotl32_(x1, 29); x1 ^= x0;
  x0 += x1; x1 = rotl32_(x1, 16); x1 ^= x0;
  x0 += x1; x1 = rotl32_(x1, 24); x1 ^= x0;
  x0 += ks2; x1 += ks0 + 2u;
  x0 += x1; x1 = rotl32_(x1, 13); x1 ^= x0;
  x0 += x1; x1 = rotl32_(x1, 15); x1 ^= x0;
  x0 += x1; x1 = rotl32_(x1, 26); x1 ^= x0;
  x0 += x1; x1 = rotl32_(x1, 6);  x1 ^= x0;
  x0 += ks0; x1 += ks1 + 3u;
  x0 += x1; x1 = rotl32_(x1, 17); x1 ^= x0;
  x0 += x1; x1 = rotl32_(x1, 29); x1 ^= x0;
  x0 += x1; x1 = rotl32_(x1, 16); x1 ^= x0;
  x0 += x1; x1 = rotl32_(x1, 24); x1 ^= x0;
  x0 += ks1; x1 += ks2 + 4u;
  x0 += x1; x1 = rotl32_(x1, 13); x1 ^= x0;
  x0 += x1; x1 = rotl32_(x1, 15); x1 ^= x0;
  x0 += x1; x1 = rotl32_(x1, 26); x1 ^= x0;
  x0 += x1; x1 = rotl32_(x1, 6);  x1 ^= x0;
  x0 += ks2; x1 += ks0 + 5u;
  *o0 = x0; *o1 = x1;
}

// --- prep: transpose w1 (48 x 128) -> w1t (128 x 48)
__global__ void prep_w1t(const float* __restrict__ w1, float* __restrict__ w1t) {
  int i = blockIdx.x * 256 + threadIdx.x;
  if (i < 48 * 128) {
    int j = i / 48, k = i % 48;
    w1t[i] = w1[k * 128 + j];
  }
}

struct SmemT {
  float xt[CHN][TH + 2][TW + 2];   // masked input tile + halo
  float Axt[TH + 4][TW + 4];       // x-tilde alpha, 12x12
  float Lf[TH + 2][TW + 2];        // life, 10x10
  float dbuf[4][64][17];           // reduce, stride 17 (conflict-free)
};

// life[10x10] = (mp3(axsrc)>0.1) & (plin>0.5)   [R3-proven dataflow]
__device__ __forceinline__ void compute_life(
    SmemT& sm, const float* __restrict__ axsrc, const float* __restrict__ plin,
    int oh, int ow, int tid)
{
  for (int i = tid; i < (TH + 4) * (TW + 4); i += 256) {
    int r = i / (TW + 4), c = i % (TW + 4);
    int gh = oh + r - 2, gw = ow + c - 2;
    sm.Axt[r][c] = (gh >= 0 && gh < HH && gw >= 0 && gw < WW)
                       ? axsrc[gh * WW + gw] : 0.f;
  }
  __syncthreads();
  for (int i = tid; i < (TH + 2) * (TW + 2); i += 256) {
    int r = i / (TW + 2), c = i % (TW + 2);
    int gh = oh + r - 1, gw = ow + c - 1;
    float life = 0.f;
    if (gh >= 0 && gh < HH && gw >= 0 && gw < WW) {
      float m = sm.Axt[r][c];
      m = fmaxf(m, sm.Axt[r][c + 1]);     m = fmaxf(m, sm.Axt[r][c + 2]);
      m = fmaxf(m, sm.Axt[r + 1][c]);     m = fmaxf(m, sm.Axt[r + 1][c + 1]);
      m = fmaxf(m, sm.Axt[r + 1][c + 2]); m = fmaxf(m, sm.Axt[r + 2][c]);
      m = fmaxf(m, sm.Axt[r + 2][c + 1]); m = fmaxf(m, sm.Axt[r + 2][c + 2]);
      if (m > 0.1f && plin[gh * WW + gw] > 0.5f) life = 1.f;
    }
    sm.Lf[r][c] = life;
  }
  __syncthreads();
}

// One NCA step for one 8x8 tile. Reads xin (+ plin if masked), writes
// xout (x-tilde, unmasked) and plout (prelife plane). R2-proven core.
__device__ __forceinline__ void step_body(
    SmemT& sm, const float* __restrict__ xin, const float* __restrict__ plin,
    const float* __restrict__ pw, const float* __restrict__ w1t,
    const float* __restrict__ b1, const float* __restrict__ w2,
    float* __restrict__ xout, float* __restrict__ plout,
    uint32_t k0, uint32_t k1, int masked, int b, int oh, int ow, int tid)
{
  const float* xb = xin + (size_t)b * PLANE;
  if (masked) compute_life(sm, xb + 3 * NPIX, plin + b * NPIX, oh, ow, tid);

  // stage 16 channels x 10x10, applying life mask if masked
  for (int i = tid; i < CHN * (TH + 2) * (TW + 2); i += 256) {
    int c  = i / ((TH + 2) * (TW + 2));
    int r  = (i / (TW + 2)) % (TH + 2);
    int cc = i % (TW + 2);
    int gh = oh + r - 1, gw = ow + cc - 1;
    float v = 0.f;
    if (gh >= 0 && gh < HH && gw >= 0 && gw < WW) {
      v = xb[(c * HH + gh) * WW + gw];
      if (masked) v *= sm.Lf[r][cc];
    }
    sm.xt[c][r][cc] = v;
  }
  __syncthreads();

  const int wv   = __builtin_amdgcn_readfirstlane((int)threadIdx.x) >> 6;
  const int lane = tid & 63;
  const int pr = lane >> 3, pc = lane & 7;
  const int jbase = wv * 32;

  // comb = [x(16) ; p(32)]: depthwise sobel pair per channel
  float comb[48];
  float premax = -1e30f;
  #pragma unroll
  for (int c = 0; c < CHN; ++c) {
    float n[9];
    #pragma unroll
    for (int dy = 0; dy < 3; ++dy)
      #pragma unroll
      for (int dx = 0; dx < 3; ++dx)
        n[dy * 3 + dx] = sm.xt[c][pr + dy][pc + dx];
    comb[c] = n[4];
    float p0 = 0.f, p1 = 0.f;
    #pragma unroll
    for (int i = 0; i < 9; ++i) {
      p0 = fmaf(pw[(2 * c) * 9 + i], n[i], p0);
      p1 = fmaf(pw[(2 * c + 1) * 9 + i], n[i], p1);
    }
    comb[16 + 2 * c] = p0;
    comb[17 + 2 * c] = p1;
    if (c == 3) {
      float m = n[0];
      #pragma unroll
      for (int i = 1; i < 9; ++i) m = fmaxf(m, n[i]);
      premax = m;
    }
  }
  #pragma unroll
  for (int k = 0; k < 48; ++k) asm volatile("" : "+v"(comb[k]));

  // j in [jbase, jbase+32), x2 unroll; weight pointers pinned to VGPR so
  // loads go down the (deeply pipelined) vector-memory path, not s_load.
  float delta[16];
  #pragma unroll
  for (int c = 0; c < 16; ++c) delta[c] = 0.f;
  for (int jj = 0; jj < 32; jj += 2) {
    const int j0 = jbase + jj;
    uintptr_t wp = (uintptr_t)(w1t + j0 * 48);
    asm("" : "+v"(wp));
    const float* wr0 = (const float*)wp;
    const float* wr1 = wr0 + 48;
    float h0 = b1[j0], h1 = b1[j0 + 1];
    #pragma unroll
    for (int k = 0; k < 48; ++k) {
      h0 = fmaf(comb[k], wr0[k], h0);
      h1 = fmaf(comb[k], wr1[k], h1);
    }
    h0 = fmaxf(h0, 0.f); h1 = fmaxf(h1, 0.f);
    uintptr_t w2p = (uintptr_t)(w2 + j0 * 16);
    asm("" : "+v"(w2p));
    const float* w20 = (const float*)w2p;
    #pragma unroll
    for (int c = 0; c < 16; ++c)
      delta[c] = fmaf(h0, w20[c], fmaf(h1, w20[16 + c], delta[c]));
  }

  // all-wave reduce; each wave then owns 4 output channels
  #pragma unroll
  for (int c = 0; c < 16; ++c) sm.dbuf[wv][lane][c] = delta[c];
  __syncthreads();

  const int gidx = (oh + pr) * WW + (ow + pc);
  uint32_t o0, o1;
  tf2x32(k0, k1, 0u, (uint32_t)(b * NPIX + gidx), &o0, &o1);
  const uint32_t bits = o0 ^ o1;
  const float u = (((bits >> 31) == 0u) && (comb[3] > 0.1f)) ? 1.f : 0.f;

  float* qb = xout + (size_t)b * PLANE;
  #pragma unroll
  for (int c2 = 0; c2 < 4; ++c2) {
    const int c = wv * 4 + c2;
    float s = delta[c];
    #pragma unroll
    for (int t = 0; t < 4; ++t)
      if (t != wv) s += sm.dbuf[t][lane][c];
    qb[c * NPIX + gidx] = fmaf(s, u, comb[c]);
  }
  if (wv == 0) plout[b * NPIX + gidx] = (premax > 0.1f) ? 1.f : 0.f;
}

// ---- cooperative: all 64 steps, grid.sync between steps
__global__ __launch_bounds__(256, 2) void nca_coop(
    const float* __restrict__ x, const float* __restrict__ pw,
    const float* __restrict__ w1t, const float* __restrict__ b1,
    const float* __restrict__ w2,
    float* __restrict__ xb0, float* __restrict__ xb1,
    float* __restrict__ pb0, float* __restrict__ pb1,
    float* __restrict__ out)
{
  __shared__ SmemT sm;
  cg::grid_group grid = cg::this_grid();

  const int tid = threadIdx.x;
  const int blk = blockIdx.x;
  const int b  = blk >> 8;
  const int oh = ((blk >> 4) & 15) * TH;
  const int ow = (blk & 15) * TW;

  float* xbuf[2] = { xb0, xb1 };
  float* pbuf[2] = { pb0, pb1 };

  for (int t = 0; t < STEPS; ++t) {
    uint32_t k0, k1;
    tf2x32(0u, 42u, 0u, (uint32_t)t, &k0, &k1);   // split(key(42))[t]
    const float* xin  = (t == 0) ? x : xbuf[(t - 1) & 1];
    const float* plin = (t == 0) ? nullptr : pbuf[(t - 1) & 1];
    step_body(sm, xin, plin, pw, w1t, b1, w2,
              xbuf[t & 1], pbuf[t & 1], k0, k1, (t > 0), b, oh, ow, tid);
    __threadfence();
    grid.sync();
  }

  // epilogue: out = x-tilde_63 * life_63
  const float* xl = xbuf[(STEPS - 1) & 1];
  const float* pl = pbuf[(STEPS - 1) & 1];
  compute_life(sm, xl + (size_t)b * PLANE + 3 * NPIX, pl + b * NPIX, oh, ow, tid);
  const int lane = tid & 63;
  const int wv = tid >> 6;
  const int pr = lane >> 3, pc = lane & 7;
  const int gidx = (oh + pr) * WW + (ow + pc);
  const float lf = sm.Lf[pr + 1][pc + 1];
  const float* qb = xl + (size_t)b * PLANE;
  float* ob = out + (size_t)b * PLANE;
  #pragma unroll
  for (int c2 = 0; c2 < 4; ++c2) {
    const int c = wv * 4 + c2;
    ob[c * NPIX + gidx] = qb[c * NPIX + gidx] * lf;
  }
}

// ---- fallback: one step per launch (same body)
__global__ __launch_bounds__(256, 2) void nca_step(
    const float* __restrict__ xin, const float* __restrict__ plin,
    const float* __restrict__ pw, const float* __restrict__ w1t,
    const float* __restrict__ b1, const float* __restrict__ w2,
    float* __restrict__ xout, float* __restrict__ plout,
    uint32_t k0, uint32_t k1, int masked)
{
  __shared__ SmemT sm;
  const int blk = blockIdx.x;
  step_body(sm, xin, plin, pw, w1t, b1, w2, xout, plout, k0, k1, masked,
            blk >> 8, ((blk >> 4) & 15) * TH, (blk & 15) * TW, threadIdx.x);
}

__global__ __launch_bounds__(256, 2) void nca_fin(
    const float* __restrict__ xl, const float* __restrict__ pl,
    float* __restrict__ out)
{
  __shared__ SmemT sm;
  const int tid = threadIdx.x;
  const int blk = blockIdx.x;
  const int b  = blk >> 8;
  const int oh = ((blk >> 4) & 15) * TH;
  const int ow = (blk & 15) * TW;
  compute_life(sm, xl + (size_t)b * PLANE + 3 * NPIX, pl + b * NPIX, oh, ow, tid);
  const int lane = tid & 63;
  const int wv = tid >> 6;
  const int pr = lane >> 3, pc = lane & 7;
  const int gidx = (oh + pr) * WW + (ow + pc);
  const float lf = sm.Lf[pr + 1][pc + 1];
  const float* qb = xl + (size_t)b * PLANE;
  float* ob = out + (size_t)b * PLANE;
  #pragma unroll
  for (int c2 = 0; c2 < 4; ++c2) {
    const int c = wv * 4 + c2;
    ob[c * NPIX + gidx] = qb[c * NPIX + gidx] * lf;
  }
}

extern "C" void kernel_launch(void* const* d_in, const int* in_sizes, int n_in,
                              void* d_out, int out_size, void* d_ws, size_t ws_size,
                              hipStream_t stream) {
  (void)in_sizes; (void)n_in; (void)out_size; (void)ws_size;
  const float* x  = (const float*)d_in[0];
  const float* pw = (const float*)d_in[1];
  const float* w1 = (const float*)d_in[2];
  const float* b1 = (const float*)d_in[3];
  const float* w2 = (const float*)d_in[4];

  float* out = (float*)d_out;
  float* ws  = (float*)d_ws;
  float* xb0 = ws;
  float* xb1 = ws + 2 * PLANE;
  float* pb0 = ws + 4 * PLANE;
  float* pb1 = ws + 4 * PLANE + 2 * NPIX;
  float* w1t = ws + 4 * PLANE + 4 * NPIX;

  prep_w1t<<<(48 * 128 + 255) / 256, 256, 0, stream>>>(w1, w1t);

  void* args[] = { (void*)&x, (void*)&pw, (void*)&w1t, (void*)&b1, (void*)&w2,
                   (void*)&xb0, (void*)&xb1, (void*)&pb0, (void*)&pb1,
                   (void*)&out };
  hipError_t ce = hipLaunchCooperativeKernel((const void*)nca_coop, dim3(512),
                                             dim3(256), args, 0, stream);
  if (ce != hipSuccess) {
    (void)hipGetLastError();   // clear sticky error, take the fallback path
    uint32_t key0[STEPS], key1[STEPS];
    for (uint32_t s = 0; s < STEPS; ++s)
      tf2x32(0u, 42u, 0u, s, &key0[s], &key1[s]);
    float* xbuf[2] = { xb0, xb1 };
    float* pbuf[2] = { pb0, pb1 };
    for (int s = 0; s < STEPS; ++s) {
      const float* src = (s == 0) ? x : xbuf[(s - 1) & 1];
      const float* pls = (s == 0) ? nullptr : pbuf[(s - 1) & 1];
      nca_step<<<dim3(512), dim3(256), 0, stream>>>(
          src, pls, pw, w1t, b1, w2, xbuf[s & 1], pbuf[s & 1],
          key0[s], key1[s], (s > 0) ? 1 : 0);
    }
    const int lf = (STEPS - 1) & 1;
    nca_fin<<<dim3(512), dim3(256), 0, stream>>>(xbuf[lf], pbuf[lf], out);
  }
}

// Round 7
// 3573.751 us; speedup vs baseline: 2.7437x; 2.7437x over previous
//
#include <hip/hip_runtime.h>
#include <stdint.h>

#define HH 128
#define WW 128
#define CHN 16
#define NPIX (HH*WW)          // 16384 per batch
#define PLANE (CHN*NPIX)      // 262144 per batch
#define STEPS 64
#define TW 8
#define TH 8

__host__ __device__ __forceinline__ uint32_t rotl32_(uint32_t x, int d) {
  return (x << d) | (x >> (32 - d));
}

__host__ __device__ __forceinline__ void tf2x32(uint32_t k0, uint32_t k1,
                                                uint32_t x0, uint32_t x1,
                                                uint32_t* o0, uint32_t* o1) {
  uint32_t ks0 = k0, ks1 = k1, ks2 = k0 ^ k1 ^ 0x1BD11BDAu;
  x0 += ks0; x1 += ks1;
  x0 += x1; x1 = rotl32_(x1, 13); x1 ^= x0;
  x0 += x1; x1 = rotl32_(x1, 15); x1 ^= x0;
  x0 += x1; x1 = rotl32_(x1, 26); x1 ^= x0;
  x0 += x1; x1 = rotl32_(x1, 6);  x1 ^= x0;
  x0 += ks1; x1 += ks2 + 1u;
  x0 += x1; x1 = rotl32_(x1, 17); x1 ^= x0;
  x0 += x1; x1 = rotl32_(x1, 29); x1 ^= x0;
  x0 += x1; x1 = rotl32_(x1, 16); x1 ^= x0;
  x0 += x1; x1 = rotl32_(x1, 24); x1 ^= x0;
  x0 += ks2; x1 += ks0 + 2u;
  x0 += x1; x1 = rotl32_(x1, 13); x1 ^= x0;
  x0 += x1; x1 = rotl32_(x1, 15); x1 ^= x0;
  x0 += x1; x1 = rotl32_(x1, 26); x1 ^= x0;
  x0 += x1; x1 = rotl32_(x1, 6);  x1 ^= x0;
  x0 += ks0; x1 += ks1 + 3u;
  x0 += x1; x1 = rotl32_(x1, 17); x1 ^= x0;
  x0 += x1; x1 = rotl32_(x1, 29); x1 ^= x0;
  x0 += x1; x1 = rotl32_(x1, 16); x1 ^= x0;
  x0 += x1; x1 = rotl32_(x1, 24); x1 ^= x0;
  x0 += ks1; x1 += ks2 + 4u;
  x0 += x1; x1 = rotl32_(x1, 13); x1 ^= x0;
  x0 += x1; x1 = rotl32_(x1, 15); x1 ^= x0;
  x0 += x1; x1 = rotl32_(x1, 26); x1 ^= x0;
  x0 += x1; x1 = rotl32_(x1, 6);  x1 ^= x0;
  x0 += ks2; x1 += ks0 + 5u;
  *o0 = x0; *o1 = x1;
}

// --- prep: transpose w1 (48 x 128) -> w1t (128 x 48)
__global__ void prep_w1t(const float* __restrict__ w1, float* __restrict__ w1t) {
  int i = blockIdx.x * 256 + threadIdx.x;
  if (i < 48 * 128) {
    int j = i / 48, k = i % 48;
    w1t[i] = w1[k * 128 + j];
  }
}

// --- fused per-step kernel: life-mask (from prev step's planes) + perceive
// + 48->128 relu + 128->16 + stochastic update. 8x8 tile, 4 waves (j/4 each).
template <int MASKED>
__global__ __launch_bounds__(256, 2) void nca_step(
    const float* __restrict__ xin, const float* __restrict__ plin,
    const float* __restrict__ pw, const float* __restrict__ w1t,
    const float* __restrict__ b1, const float* __restrict__ w2,
    float* __restrict__ xout, float* __restrict__ plout,
    uint32_t k0, uint32_t k1)
{
  __shared__ float xt[CHN][TH + 2][TW + 2];  // staged tile (masked in-place)
  __shared__ float Axt[TH + 4][TW + 4];      // prev x-tilde alpha, 12x12
  __shared__ float Lf[TH + 2][TW + 2];       // life, 10x10
  __shared__ float dbuf[4][64][17];          // reduce (stride 17: 2-way max)
  __shared__ float uLDS[64];                 // RNG gate, wave0 -> all

  const int tid = threadIdx.x;
  const int blk = blockIdx.x;
  const int b  = blk >> 8;
  const int oh = ((blk >> 4) & 15) * TH;
  const int ow = (blk & 15) * TW;
  const float* xb = xin + (size_t)b * PLANE;

  // ---- phase 1: ALL global loads up front (deep vmcnt overlap)
  if (MASKED) {
    const float* ax = xb + 3 * NPIX;
    for (int i = tid; i < (TH + 4) * (TW + 4); i += 256) {
      int r = i / (TW + 4), c = i % (TW + 4);
      int gh = oh + r - 2, gw = ow + c - 2;
      Axt[r][c] = (gh >= 0 && gh < HH && gw >= 0 && gw < WW)
                      ? ax[gh * WW + gw] : 0.f;
    }
  }
  for (int i = tid; i < CHN * (TH + 2) * (TW + 2); i += 256) {
    int c  = i / ((TH + 2) * (TW + 2));
    int r  = (i / (TW + 2)) % (TH + 2);
    int cc = i % (TW + 2);
    int gh = oh + r - 1, gw = ow + cc - 1;
    xt[c][r][cc] = (gh >= 0 && gh < HH && gw >= 0 && gw < WW)
                       ? xb[(c * HH + gh) * WW + gw] : 0.f;
  }
  __syncthreads();

  // ---- phase 2 (masked only): life = (mp3(Axt)>0.1) & (plin>0.5); mask xt
  if (MASKED) {
    const float* pl = plin + b * NPIX;
    for (int i = tid; i < (TH + 2) * (TW + 2); i += 256) {
      int r = i / (TW + 2), c = i % (TW + 2);
      int gh = oh + r - 1, gw = ow + c - 1;
      float life = 0.f;
      if (gh >= 0 && gh < HH && gw >= 0 && gw < WW) {
        float m = Axt[r][c];
        m = fmaxf(m, Axt[r][c + 1]);     m = fmaxf(m, Axt[r][c + 2]);
        m = fmaxf(m, Axt[r + 1][c]);     m = fmaxf(m, Axt[r + 1][c + 1]);
        m = fmaxf(m, Axt[r + 1][c + 2]); m = fmaxf(m, Axt[r + 2][c]);
        m = fmaxf(m, Axt[r + 2][c + 1]); m = fmaxf(m, Axt[r + 2][c + 2]);
        if (m > 0.1f && pl[gh * WW + gw] > 0.5f) life = 1.f;
      }
      Lf[r][c] = life;
    }
    __syncthreads();
    for (int i = tid; i < CHN * (TH + 2) * (TW + 2); i += 256) {
      int c  = i / ((TH + 2) * (TW + 2));
      int rc = i % ((TH + 2) * (TW + 2));
      int r = rc / (TW + 2), cc = rc % (TW + 2);
      xt[c][r][cc] *= Lf[r][cc];
    }
    __syncthreads();
  }

  const int wv   = __builtin_amdgcn_readfirstlane((int)threadIdx.x) >> 6;
  const int lane = tid & 63;
  const int pr = lane >> 3, pc = lane & 7;
  const int jbase = wv * 32;
  const int gidx = (oh + pr) * WW + (ow + pc);

  // ---- perceive: comb = [x(16) ; sobel pair(32)]
  float comb[48];
  float premax = -1e30f;
  #pragma unroll
  for (int c = 0; c < CHN; ++c) {
    float n[9];
    #pragma unroll
    for (int dy = 0; dy < 3; ++dy)
      #pragma unroll
      for (int dx = 0; dx < 3; ++dx)
        n[dy * 3 + dx] = xt[c][pr + dy][pc + dx];
    comb[c] = n[4];
    float p0 = 0.f, p1 = 0.f;
    #pragma unroll
    for (int i = 0; i < 9; ++i) {
      p0 = fmaf(pw[(2 * c) * 9 + i], n[i], p0);
      p1 = fmaf(pw[(2 * c + 1) * 9 + i], n[i], p1);
    }
    comb[16 + 2 * c] = p0;
    comb[17 + 2 * c] = p1;
    if (c == 3) {
      float m = n[0];
      #pragma unroll
      for (int i = 1; i < 9; ++i) m = fmaxf(m, n[i]);
      premax = m;
    }
  }
  #pragma unroll
  for (int k = 0; k < 48; ++k) asm volatile("" : "+v"(comb[k]));

  // ---- j-loop: j in [jbase, jbase+32), pair-unrolled; weights via
  // VGPR-pinned float4 vector loads (L1-resident, vmcnt-pipelined)
  float delta[16];
  #pragma unroll
  for (int c = 0; c < 16; ++c) delta[c] = 0.f;
  for (int jj = 0; jj < 32; jj += 2) {
    const int j0 = jbase + jj;
    uintptr_t wp = (uintptr_t)(w1t + j0 * 48);
    asm("" : "+v"(wp));
    const float4* w4 = (const float4*)wp;     // rows j0 (0..11), j0+1 (12..23)
    float h0 = b1[j0], h1 = b1[j0 + 1];
    #pragma unroll
    for (int q = 0; q < 12; ++q) {
      const float4 a = w4[q];
      const float4 bq = w4[q + 12];
      const float c0 = comb[4 * q], c1 = comb[4 * q + 1];
      const float c2 = comb[4 * q + 2], c3 = comb[4 * q + 3];
      h0 = fmaf(c0, a.x, h0);  h0 = fmaf(c1, a.y, h0);
      h0 = fmaf(c2, a.z, h0);  h0 = fmaf(c3, a.w, h0);
      h1 = fmaf(c0, bq.x, h1); h1 = fmaf(c1, bq.y, h1);
      h1 = fmaf(c2, bq.z, h1); h1 = fmaf(c3, bq.w, h1);
    }
    h0 = fmaxf(h0, 0.f); h1 = fmaxf(h1, 0.f);
    uintptr_t w2p = (uintptr_t)(w2 + j0 * 16);
    asm("" : "+v"(w2p));
    const float4* v4 = (const float4*)w2p;    // rows j0 (0..3), j0+1 (4..7)
    #pragma unroll
    for (int q = 0; q < 4; ++q) {
      const float4 a = v4[q];
      const float4 bq = v4[q + 4];
      delta[4 * q]     = fmaf(h0, a.x, fmaf(h1, bq.x, delta[4 * q]));
      delta[4 * q + 1] = fmaf(h0, a.y, fmaf(h1, bq.y, delta[4 * q + 1]));
      delta[4 * q + 2] = fmaf(h0, a.z, fmaf(h1, bq.z, delta[4 * q + 2]));
      delta[4 * q + 3] = fmaf(h0, a.w, fmaf(h1, bq.w, delta[4 * q + 3]));
    }
  }

  // ---- reduce: publish partials; wave0 computes RNG gate meanwhile
  #pragma unroll
  for (int c = 0; c < 16; ++c) dbuf[wv][lane][c] = delta[c];
  if (wv == 0) {
    uint32_t o0, o1;
    tf2x32(k0, k1, 0u, (uint32_t)(b * NPIX + gidx), &o0, &o1);
    const uint32_t bits = o0 ^ o1;
    uLDS[lane] = (((bits >> 31) == 0u) && (comb[3] > 0.1f)) ? 1.f : 0.f;
  }
  __syncthreads();

  const float u = uLDS[lane];
  float* qb = xout + (size_t)b * PLANE;
  #pragma unroll
  for (int c2 = 0; c2 < 4; ++c2) {
    const int c = wv * 4 + c2;
    float s = delta[c];
    #pragma unroll
    for (int t = 0; t < 4; ++t)
      if (t != wv) s += dbuf[t][lane][c];
    qb[c * NPIX + gidx] = fmaf(s, u, comb[c]);
  }
  if (wv == 0) plout[b * NPIX + gidx] = (premax > 0.1f) ? 1.f : 0.f;
}

// --- final: out = x-tilde_63 * (mp3(x-tilde_63 alpha)>0.1 & prelife_63)
// Pixel (oh+pr, ow+pc) window in Axt coords: rows pr+1..pr+3, cols pc+1..pc+3
// (Axt[r][c] = alpha(oh+r-2, ow+c-2)).  [R6 bug: used pr..pr+2 — off by one]
__global__ __launch_bounds__(256, 2) void nca_fin(
    const float* __restrict__ xl, const float* __restrict__ pl,
    float* __restrict__ out)
{
  __shared__ float Axt[TH + 4][TW + 4];
  const int tid = threadIdx.x;
  const int blk = blockIdx.x;
  const int b  = blk >> 8;
  const int oh = ((blk >> 4) & 15) * TH;
  const int ow = (blk & 15) * TW;
  const float* ax = xl + (size_t)b * PLANE + 3 * NPIX;
  for (int i = tid; i < (TH + 4) * (TW + 4); i += 256) {
    int r = i / (TW + 4), c = i % (TW + 4);
    int gh = oh + r - 2, gw = ow + c - 2;
    Axt[r][c] = (gh >= 0 && gh < HH && gw >= 0 && gw < WW)
                    ? ax[gh * WW + gw] : 0.f;
  }
  __syncthreads();
  const int wv = tid >> 6, lane = tid & 63;
  const int pr = lane >> 3, pc = lane & 7;
  const int gidx = (oh + pr) * WW + (ow + pc);
  float m = Axt[pr + 1][pc + 1];
  #pragma unroll
  for (int dy = 0; dy < 3; ++dy)
    #pragma unroll
    for (int dx = 0; dx < 3; ++dx)
      m = fmaxf(m, Axt[pr + 1 + dy][pc + 1 + dx]);
  const float lf = (m > 0.1f && pl[b * NPIX + gidx] > 0.5f) ? 1.f : 0.f;
  const float* qb = xl + (size_t)b * PLANE;
  float* ob = out + (size_t)b * PLANE;
  #pragma unroll
  for (int c2 = 0; c2 < 4; ++c2) {
    const int c = wv * 4 + c2;
    ob[c * NPIX + gidx] = qb[c * NPIX + gidx] * lf;
  }
}

extern "C" void kernel_launch(void* const* d_in, const int* in_sizes, int n_in,
                              void* d_out, int out_size, void* d_ws, size_t ws_size,
                              hipStream_t stream) {
  (void)in_sizes; (void)n_in; (void)out_size; (void)ws_size;
  const float* x  = (const float*)d_in[0];
  const float* pw = (const float*)d_in[1];
  const float* w1 = (const float*)d_in[2];
  const float* b1 = (const float*)d_in[3];
  const float* w2 = (const float*)d_in[4];

  float* out = (float*)d_out;
  float* ws  = (float*)d_ws;
  float* xb0 = ws;
  float* xb1 = ws + 2 * PLANE;
  float* pb0 = ws + 4 * PLANE;
  float* pb1 = ws + 4 * PLANE + 2 * NPIX;
  float* w1t = ws + 4 * PLANE + 4 * NPIX;

  prep_w1t<<<(48 * 128 + 255) / 256, 256, 0, stream>>>(w1, w1t);

  uint32_t key0[STEPS], key1[STEPS];
  for (uint32_t s = 0; s < STEPS; ++s)
    tf2x32(0u, 42u, 0u, s, &key0[s], &key1[s]);   // split(key(42)) partitionable

  float* xbuf[2] = { xb0, xb1 };
  float* pbuf[2] = { pb0, pb1 };
  nca_step<0><<<dim3(512), dim3(256), 0, stream>>>(
      x, nullptr, pw, w1t, b1, w2, xbuf[0], pbuf[0], key0[0], key1[0]);
  for (int s = 1; s < STEPS; ++s) {
    nca_step<1><<<dim3(512), dim3(256), 0, stream>>>(
        xbuf[(s - 1) & 1], pbuf[(s - 1) & 1], pw, w1t, b1, w2,
        xbuf[s & 1], pbuf[s & 1], key0[s], key1[s]);
  }
  const int lf = (STEPS - 1) & 1;
  nca_fin<<<dim3(512), dim3(256), 0, stream>>>(xbuf[lf], pbuf[lf], out);
}

// Round 8
// 1252.358 us; speedup vs baseline: 7.8296x; 2.8536x over previous
//
#include <hip/hip_runtime.h>
#include <stdint.h>

#define HH 128
#define WW 128
#define CHN 16
#define NPIX (HH*WW)          // 16384 per batch
#define PLANE (CHN*NPIX)      // 262144 per batch
#define STEPS 64
#define TW 8
#define TH 8

__host__ __device__ __forceinline__ uint32_t rotl32_(uint32_t x, int d) {
  return (x << d) | (x >> (32 - d));
}

__host__ __device__ __forceinline__ void tf2x32(uint32_t k0, uint32_t k1,
                                                uint32_t x0, uint32_t x1,
                                                uint32_t* o0, uint32_t* o1) {
  uint32_t ks0 = k0, ks1 = k1, ks2 = k0 ^ k1 ^ 0x1BD11BDAu;
  x0 += ks0; x1 += ks1;
  x0 += x1; x1 = rotl32_(x1, 13); x1 ^= x0;
  x0 += x1; x1 = rotl32_(x1, 15); x1 ^= x0;
  x0 += x1; x1 = rotl32_(x1, 26); x1 ^= x0;
  x0 += x1; x1 = rotl32_(x1, 6);  x1 ^= x0;
  x0 += ks1; x1 += ks2 + 1u;
  x0 += x1; x1 = rotl32_(x1, 17); x1 ^= x0;
  x0 += x1; x1 = rotl32_(x1, 29); x1 ^= x0;
  x0 += x1; x1 = rotl32_(x1, 16); x1 ^= x0;
  x0 += x1; x1 = rotl32_(x1, 24); x1 ^= x0;
  x0 += ks2; x1 += ks0 + 2u;
  x0 += x1; x1 = rotl32_(x1, 13); x1 ^= x0;
  x0 += x1; x1 = rotl32_(x1, 15); x1 ^= x0;
  x0 += x1; x1 = rotl32_(x1, 26); x1 ^= x0;
  x0 += x1; x1 = rotl32_(x1, 6);  x1 ^= x0;
  x0 += ks0; x1 += ks1 + 3u;
  x0 += x1; x1 = rotl32_(x1, 17); x1 ^= x0;
  x0 += x1; x1 = rotl32_(x1, 29); x1 ^= x0;
  x0 += x1; x1 = rotl32_(x1, 16); x1 ^= x0;
  x0 += x1; x1 = rotl32_(x1, 24); x1 ^= x0;
  x0 += ks1; x1 += ks2 + 4u;
  x0 += x1; x1 = rotl32_(x1, 13); x1 ^= x0;
  x0 += x1; x1 = rotl32_(x1, 15); x1 ^= x0;
  x0 += x1; x1 = rotl32_(x1, 26); x1 ^= x0;
  x0 += x1; x1 = rotl32_(x1, 6);  x1 ^= x0;
  x0 += ks2; x1 += ks0 + 5u;
  *o0 = x0; *o1 = x1;
}

// --- prep: transpose w1 (48 x 128) -> w1t (128 x 48)
__global__ void prep_w1t(const float* __restrict__ w1, float* __restrict__ w1t) {
  int i = blockIdx.x * 256 + threadIdx.x;
  if (i < 48 * 128) {
    int j = i / 48, k = i % 48;
    w1t[i] = w1[k * 128 + j];
  }
}

// --- fused per-step kernel. 8x8 pixel tile, 512 threads = 8 waves.
// Conv is channel-split across waves (wave w -> channels 2w,2w+1) into a
// shared comb[64][49] array; j-loop is split x8 (16 hidden units per wave);
// weights read via plain indexing -> scalar s_load broadcast (R7 lesson:
// never pin wave-uniform pointers into VGPRs).
template <int MASKED>
__global__ __launch_bounds__(512, 4) void nca_step(
    const float* __restrict__ xin, const float* __restrict__ plin,
    const float* __restrict__ pw, const float* __restrict__ w1t,
    const float* __restrict__ b1, const float* __restrict__ w2,
    float* __restrict__ xout, float* __restrict__ plout,
    uint32_t k0, uint32_t k1)
{
  __shared__ float xt[CHN][TH + 2][TW + 2];  // staged tile (masked in-place)
  __shared__ float Axt[TH + 4][TW + 4];      // prev x-tilde alpha, 12x12
  __shared__ float Lf[TH + 2][TW + 2];       // life, 10x10
  __shared__ float combS[64][49];            // per-pixel comb (pad 49: CF)
  __shared__ float dbuf[8][64][17];          // 8-way reduce (stride 17: CF)
  __shared__ float uLDS[64];                 // RNG gate, wave0 -> all

  const int tid = threadIdx.x;
  const int blk = blockIdx.x;
  const int b  = blk >> 8;
  const int oh = ((blk >> 4) & 15) * TH;
  const int ow = (blk & 15) * TW;
  const float* xb = xin + (size_t)b * PLANE;

  // ---- phase 1: global loads up front
  if (MASKED) {
    const float* ax = xb + 3 * NPIX;
    for (int i = tid; i < (TH + 4) * (TW + 4); i += 512) {
      int r = i / (TW + 4), c = i % (TW + 4);
      int gh = oh + r - 2, gw = ow + c - 2;
      Axt[r][c] = (gh >= 0 && gh < HH && gw >= 0 && gw < WW)
                      ? ax[gh * WW + gw] : 0.f;
    }
  }
  for (int i = tid; i < CHN * (TH + 2) * (TW + 2); i += 512) {
    int c  = i / ((TH + 2) * (TW + 2));
    int r  = (i / (TW + 2)) % (TH + 2);
    int cc = i % (TW + 2);
    int gh = oh + r - 1, gw = ow + cc - 1;
    xt[c][r][cc] = (gh >= 0 && gh < HH && gw >= 0 && gw < WW)
                       ? xb[(c * HH + gh) * WW + gw] : 0.f;
  }
  __syncthreads();

  // ---- phase 2 (masked only): life = (mp3(Axt)>0.1) & (plin>0.5); mask xt
  if (MASKED) {
    const float* pl = plin + b * NPIX;
    for (int i = tid; i < (TH + 2) * (TW + 2); i += 512) {
      int r = i / (TW + 2), c = i % (TW + 2);
      int gh = oh + r - 1, gw = ow + c - 1;
      float life = 0.f;
      if (gh >= 0 && gh < HH && gw >= 0 && gw < WW) {
        float m = Axt[r][c];
        m = fmaxf(m, Axt[r][c + 1]);     m = fmaxf(m, Axt[r][c + 2]);
        m = fmaxf(m, Axt[r + 1][c]);     m = fmaxf(m, Axt[r + 1][c + 1]);
        m = fmaxf(m, Axt[r + 1][c + 2]); m = fmaxf(m, Axt[r + 2][c]);
        m = fmaxf(m, Axt[r + 2][c + 1]); m = fmaxf(m, Axt[r + 2][c + 2]);
        if (m > 0.1f && pl[gh * WW + gw] > 0.5f) life = 1.f;
      }
      Lf[r][c] = life;
    }
    __syncthreads();
    for (int i = tid; i < CHN * (TH + 2) * (TW + 2); i += 512) {
      int c  = i / ((TH + 2) * (TW + 2));
      int rc = i % ((TH + 2) * (TW + 2));
      int r = rc / (TW + 2), cc = rc % (TW + 2);
      xt[c][r][cc] *= Lf[r][cc];
    }
    __syncthreads();
  }

  const int wv   = __builtin_amdgcn_readfirstlane((int)threadIdx.x) >> 6;
  const int lane = tid & 63;
  const int pr = lane >> 3, pc = lane & 7;     // pixel = lane
  const int gidx = (oh + pr) * WW + (ow + pc);

  // ---- conv, channel-split: wave w computes channels 2w, 2w+1 for all px
  {
    const int cA = 2 * wv, cB = 2 * wv + 1;
    float nA[9], nB[9];
    #pragma unroll
    for (int dy = 0; dy < 3; ++dy)
      #pragma unroll
      for (int dx = 0; dx < 3; ++dx) {
        nA[dy * 3 + dx] = xt[cA][pr + dy][pc + dx];
        nB[dy * 3 + dx] = xt[cB][pr + dy][pc + dx];
      }
    float pA0 = 0.f, pA1 = 0.f, pB0 = 0.f, pB1 = 0.f;
    #pragma unroll
    for (int i = 0; i < 9; ++i) {
      pA0 = fmaf(pw[(2 * cA) * 9 + i],     nA[i], pA0);
      pA1 = fmaf(pw[(2 * cA + 1) * 9 + i], nA[i], pA1);
      pB0 = fmaf(pw[(2 * cB) * 9 + i],     nB[i], pB0);
      pB1 = fmaf(pw[(2 * cB + 1) * 9 + i], nB[i], pB1);
    }
    combS[lane][cA] = nA[4];
    combS[lane][cB] = nB[4];
    combS[lane][16 + 2 * cA] = pA0;
    combS[lane][17 + 2 * cA] = pA1;
    combS[lane][16 + 2 * cB] = pB0;
    combS[lane][17 + 2 * cB] = pB1;
    if (wv == 1) {   // cB == 3: alpha channel -> prelife
      float m = nB[0];
      #pragma unroll
      for (int i = 1; i < 9; ++i) m = fmaxf(m, nB[i]);
      plout[b * NPIX + gidx] = (m > 0.1f) ? 1.f : 0.f;
    }
  }
  __syncthreads();

  // ---- load own pixel's comb into registers (stride-49: conflict-free)
  float comb[48];
  #pragma unroll
  for (int k = 0; k < 48; ++k) comb[k] = combS[lane][k];
  #pragma unroll
  for (int k = 0; k < 48; ++k) asm volatile("" : "+v"(comb[k]));

  // wave 0: RNG gate (overlaps other waves' j-loops)
  if (wv == 0) {
    uint32_t o0, o1;
    tf2x32(k0, k1, 0u, (uint32_t)(b * NPIX + gidx), &o0, &o1);
    const uint32_t bits = o0 ^ o1;
    uLDS[lane] = (((bits >> 31) == 0u) && (comb[3] > 0.1f)) ? 1.f : 0.f;
  }

  // ---- j-loop: wave w owns j in [16w, 16w+16), pair-unrolled; weights via
  // plain indexing (wave-uniform -> scalar broadcast loads)
  const int jbase = wv * 16;
  float delta[16];
  #pragma unroll
  for (int c = 0; c < 16; ++c) delta[c] = 0.f;
  for (int jj = 0; jj < 16; jj += 2) {
    const int j0 = jbase + jj;
    const float* wr0 = w1t + j0 * 48;
    const float* wr1 = wr0 + 48;
    float h0 = b1[j0], h1 = b1[j0 + 1];
    #pragma unroll
    for (int k = 0; k < 48; ++k) {
      h0 = fmaf(comb[k], wr0[k], h0);
      h1 = fmaf(comb[k], wr1[k], h1);
    }
    h0 = fmaxf(h0, 0.f); h1 = fmaxf(h1, 0.f);
    const float* w20 = w2 + j0 * 16;
    #pragma unroll
    for (int c = 0; c < 16; ++c)
      delta[c] = fmaf(h0, w20[c], fmaf(h1, w20[16 + c], delta[c]));
  }

  // ---- 8-way reduce; each wave then owns 2 output channels
  #pragma unroll
  for (int c = 0; c < 16; ++c) dbuf[wv][lane][c] = delta[c];
  __syncthreads();

  const float u = uLDS[lane];
  float* qb = xout + (size_t)b * PLANE;
  #pragma unroll
  for (int c2 = 0; c2 < 2; ++c2) {
    const int c = 2 * wv + c2;
    float s = dbuf[0][lane][c];
    #pragma unroll
    for (int t = 1; t < 8; ++t) s += dbuf[t][lane][c];
    qb[c * NPIX + gidx] = fmaf(s, u, comb[c]);
  }
}

// --- final: out = x-tilde_63 * (mp3(x-tilde_63 alpha)>0.1 & prelife_63)
// Pixel (oh+pr, ow+pc) window in Axt coords: rows pr+1..pr+3 (R7-proven).
__global__ __launch_bounds__(256, 2) void nca_fin(
    const float* __restrict__ xl, const float* __restrict__ pl,
    float* __restrict__ out)
{
  __shared__ float Axt[TH + 4][TW + 4];
  const int tid = threadIdx.x;
  const int blk = blockIdx.x;
  const int b  = blk >> 8;
  const int oh = ((blk >> 4) & 15) * TH;
  const int ow = (blk & 15) * TW;
  const float* ax = xl + (size_t)b * PLANE + 3 * NPIX;
  for (int i = tid; i < (TH + 4) * (TW + 4); i += 256) {
    int r = i / (TW + 4), c = i % (TW + 4);
    int gh = oh + r - 2, gw = ow + c - 2;
    Axt[r][c] = (gh >= 0 && gh < HH && gw >= 0 && gw < WW)
                    ? ax[gh * WW + gw] : 0.f;
  }
  __syncthreads();
  const int wv = tid >> 6, lane = tid & 63;
  const int pr = lane >> 3, pc = lane & 7;
  const int gidx = (oh + pr) * WW + (ow + pc);
  float m = Axt[pr + 1][pc + 1];
  #pragma unroll
  for (int dy = 0; dy < 3; ++dy)
    #pragma unroll
    for (int dx = 0; dx < 3; ++dx)
      m = fmaxf(m, Axt[pr + 1 + dy][pc + 1 + dx]);
  const float lf = (m > 0.1f && pl[b * NPIX + gidx] > 0.5f) ? 1.f : 0.f;
  const float* qb = xl + (size_t)b * PLANE;
  float* ob = out + (size_t)b * PLANE;
  #pragma unroll
  for (int c2 = 0; c2 < 4; ++c2) {
    const int c = wv * 4 + c2;
    ob[c * NPIX + gidx] = qb[c * NPIX + gidx] * lf;
  }
}

extern "C" void kernel_launch(void* const* d_in, const int* in_sizes, int n_in,
                              void* d_out, int out_size, void* d_ws, size_t ws_size,
                              hipStream_t stream) {
  (void)in_sizes; (void)n_in; (void)out_size; (void)ws_size;
  const float* x  = (const float*)d_in[0];
  const float* pw = (const float*)d_in[1];
  const float* w1 = (const float*)d_in[2];
  const float* b1 = (const float*)d_in[3];
  const float* w2 = (const float*)d_in[4];

  float* out = (float*)d_out;
  float* ws  = (float*)d_ws;
  float* xb0 = ws;
  float* xb1 = ws + 2 * PLANE;
  float* pb0 = ws + 4 * PLANE;
  float* pb1 = ws + 4 * PLANE + 2 * NPIX;
  float* w1t = ws + 4 * PLANE + 4 * NPIX;

  prep_w1t<<<(48 * 128 + 255) / 256, 256, 0, stream>>>(w1, w1t);

  uint32_t key0[STEPS], key1[STEPS];
  for (uint32_t s = 0; s < STEPS; ++s)
    tf2x32(0u, 42u, 0u, s, &key0[s], &key1[s]);   // split(key(42)) partitionable

  float* xbuf[2] = { xb0, xb1 };
  float* pbuf[2] = { pb0, pb1 };
  nca_step<0><<<dim3(512), dim3(512), 0, stream>>>(
      x, nullptr, pw, w1t, b1, w2, xbuf[0], pbuf[0], key0[0], key1[0]);
  for (int s = 1; s < STEPS; ++s) {
    nca_step<1><<<dim3(512), dim3(512), 0, stream>>>(
        xbuf[(s - 1) & 1], pbuf[(s - 1) & 1], pw, w1t, b1, w2,
        xbuf[s & 1], pbuf[s & 1], key0[s], key1[s]);
  }
  const int lf = (STEPS - 1) & 1;
  nca_fin<<<dim3(512), dim3(256), 0, stream>>>(xbuf[lf], pbuf[lf], out);
}